// Round 3
// baseline (209.072 us; speedup 1.0000x reference)
//
#include <hip/hip_runtime.h>

#define B_  8
#define C_  64
#define H_  128
#define W_  128
#define HW_ (H_*W_)

typedef __attribute__((ext_vector_type(4))) float f32x4;
typedef __attribute__((ext_vector_type(8))) short short8;

static __device__ __forceinline__ unsigned short f2bf(float f) {
  unsigned int u = __float_as_uint(f);
  u += 0x7fff + ((u >> 16) & 1);   // round-to-nearest-even
  return (unsigned short)(u >> 16);
}

// ---------------- kernel 0: reorder conv3x3 weights into MFMA A-fragments ----
// afrag layout: [(octile*9+kk)*2+ks][lane][8] bf16
// A[m][k] for sub-GEMM kk: m = oc (octile*16 + lane&15), k = ic (ks*32 + (lane>>4)*8 + j)
__global__ void k0_prep(const float* __restrict__ w, unsigned short* __restrict__ afrag) {
  int idx = blockIdx.x * 256 + threadIdx.x;
  if (idx >= 4 * 9 * 2 * 64 * 8) return;
  int j     = idx & 7;
  int lane  = (idx >> 3) & 63;
  int fs    = idx >> 9;
  int ks    = fs & 1;
  int kk    = (fs >> 1) % 9;
  int octile = fs / 18;
  int oc = octile * 16 + (lane & 15);
  int ic = ks * 32 + (lane >> 4) * 8 + j;
  afrag[idx] = f2bf(w[(oc * 64 + ic) * 9 + kk]);
}

// ---------------- kernel 1: fused kernel-gen + involution ----------------
// one thread per pixel; writes involution result NHWC bf16 [B][H][W][64]
__global__ __launch_bounds__(256) void k1_fused(
    const float* __restrict__ guide, const float* __restrict__ target,
    const float* __restrict__ w_reduce, const float* __restrict__ bn1g,
    const float* __restrict__ bn1b, const float* __restrict__ bn1m,
    const float* __restrict__ bn1v, const float* __restrict__ w_span,
    const float* __restrict__ b_span, unsigned short* __restrict__ inv) {
  __shared__ f32x4 s_wred[64][4];   // [c][q]: w_reduce[r=4q+..][c]
  __shared__ f32x4 s_wspan[18][4];  // [j][q]: w_span[j][r=4q+..]
  __shared__ float s_s1[16], s_sh1[16], s_bsp[18];
  int t = threadIdx.x;
  for (int i = t; i < 1024; i += 256) {
    int c = i >> 4, r = i & 15;
    ((float*)&s_wred[c][0])[r] = w_reduce[r * 64 + c];
  }
  for (int i = t; i < 288; i += 256) {
    int j = i / 16, r = i % 16;
    ((float*)&s_wspan[j][0])[r] = w_span[j * 16 + r];
  }
  if (t < 16) {
    float s = bn1g[t] * rsqrtf(bn1v[t] + 1e-5f);
    s_s1[t]  = s;
    s_sh1[t] = bn1b[t] - bn1m[t] * s;
  }
  if (t < 18) s_bsp[t] = b_span[t];
  __syncthreads();

  int b = blockIdx.z;
  int h = blockIdx.y * 16 + (t >> 4);
  int w = blockIdx.x * 16 + (t & 15);
  const float* gp = guide  + (size_t)b * C_ * HW_ + h * W_ + w;
  const float* tp = target + (size_t)b * C_ * HW_ + h * W_ + w;

  f32x4 xr[4];
  xr[0] = 0.f; xr[1] = 0.f; xr[2] = 0.f; xr[3] = 0.f;
  #pragma unroll 8
  for (int c = 0; c < 64; ++c) {
    float v = gp[c * HW_] + tp[c * HW_];
    #pragma unroll
    for (int q = 0; q < 4; ++q) xr[q] += s_wred[c][q] * v;
  }
  #pragma unroll
  for (int q = 0; q < 4; ++q) {
    #pragma unroll
    for (int r = 0; r < 4; ++r) {
      float x = xr[q][r] * s_s1[q * 4 + r] + s_sh1[q * 4 + r];
      xr[q][r] = fmaxf(x, 0.f);
    }
  }
  float kern[18];
  #pragma unroll
  for (int j = 0; j < 18; ++j) {
    f32x4 a = s_wspan[j][0] * xr[0] + s_wspan[j][1] * xr[1]
            + s_wspan[j][2] * xr[2] + s_wspan[j][3] * xr[3];
    kern[j] = s_bsp[j] + a[0] + a[1] + a[2] + a[3];
  }

  // involution: out[c] = sum_k kern[(c>>5)*9+k] * target[c][h+di-1][w+dj-1]
  size_t obase = (((size_t)b * H_ + h) * W_ + w) * 64;
  const float* tb = target + (size_t)b * C_ * HW_;
  for (int c8 = 0; c8 < 8; ++c8) {
    short8 pv;
    #pragma unroll
    for (int ci = 0; ci < 8; ++ci) {
      int c = c8 * 8 + ci;
      const float* tc = tb + (size_t)c * HW_;
      const float* kb = &kern[(c >> 5) * 9];
      float acc = 0.f;
      #pragma unroll
      for (int di = 0; di < 3; ++di) {
        int hh = h + di - 1;
        bool hok = (unsigned)hh < (unsigned)H_;
        #pragma unroll
        for (int dj = 0; dj < 3; ++dj) {
          int ww = w + dj - 1;
          float tv = (hok && (unsigned)ww < (unsigned)W_) ? tc[hh * W_ + ww] : 0.f;
          acc += kb[di * 3 + dj] * tv;
        }
      }
      pv[ci] = (short)f2bf(acc);
    }
    *(short8*)(inv + obase + c8 * 8) = pv;
  }
}

// ---------------- kernel 2: 3x3 conv (bf16 MFMA) + BN3 + ReLU ----------------
// block = 256 threads = 4 waves; each wave owns one 16-oc tile.
// pixel tile: 8 rows x 32 cols; LDS tile 10 x 34 cells x 64ch bf16, XOR-swizzled.
__global__ __launch_bounds__(256) void k2_conv(
    const unsigned short* __restrict__ inv, const unsigned short* __restrict__ afrag,
    const float* __restrict__ bn3g, const float* __restrict__ bn3b,
    const float* __restrict__ bn3m, const float* __restrict__ bn3v,
    float* __restrict__ out) {
  __shared__ unsigned short tile[340 * 64];  // 43520 B
  int t = threadIdx.x;
  int b  = blockIdx.z;
  int h0 = blockIdx.y * 8;
  int w0 = blockIdx.x * 32;

  // stage inv tile with halo; swizzle: 16B chunk index XOR (cell_col & 7)
  for (int idx = t; idx < 340 * 8; idx += 256) {
    int cell = idx >> 3, chunk = idx & 7;
    int r = cell / 34, c = cell - r * 34;
    int hh = h0 + r - 1, ww = w0 + c - 1;
    short8 val = {0, 0, 0, 0, 0, 0, 0, 0};
    if ((unsigned)hh < (unsigned)H_ && (unsigned)ww < (unsigned)W_)
      val = *(const short8*)(inv + ((((size_t)b * H_ + hh) * W_ + ww) << 6) + chunk * 8);
    *(short8*)&tile[cell * 64 + ((chunk ^ (c & 7)) * 8)] = val;
  }

  int wave = t >> 6, lane = t & 63;
  // A fragments (weights) in registers: 18 frags x 16B = 72 VGPRs
  short8 A[18];
  #pragma unroll
  for (int f = 0; f < 18; ++f)
    A[f] = *(const short8*)(afrag + (((size_t)wave * 18 + f) * 64 + lane) * 8);

  // BN3 scale/shift for this lane's 4 output channels
  f32x4 s3, sh3;
  #pragma unroll
  for (int r = 0; r < 4; ++r) {
    int oc = wave * 16 + (lane >> 4) * 4 + r;
    float s = bn3g[oc] * rsqrtf(bn3v[oc] + 1e-5f);
    s3[r]  = s;
    sh3[r] = bn3b[oc] - bn3m[oc] * s;
  }
  __syncthreads();

  #pragma unroll 2
  for (int nt = 0; nt < 16; ++nt) {
    int trow = nt >> 1;
    int tcol = (nt & 1) * 16;
    f32x4 acc = {0.f, 0.f, 0.f, 0.f};
    #pragma unroll
    for (int kk = 0; kk < 9; ++kk) {
      int di = kk / 3, dj = kk - di * 3;
      int wcell = tcol + (lane & 15) + dj;          // 0..33
      int cellbase = (trow + di) * 34 + wcell;
      #pragma unroll
      for (int ks = 0; ks < 2; ++ks) {
        int sw = (ks * 4 + (lane >> 4)) ^ (wcell & 7);
        short8 bf = *(const short8*)&tile[cellbase * 64 + sw * 8];
        acc = __builtin_amdgcn_mfma_f32_16x16x32_bf16(A[kk * 2 + ks], bf, acc, 0, 0, 0);
      }
    }
    // epilogue: BN + ReLU, write NCHW f32
    int h = h0 + trow, w = w0 + tcol + (lane & 15);
    float* op = out + ((size_t)b * C_ + wave * 16 + (lane >> 4) * 4) * HW_ + h * W_ + w;
    #pragma unroll
    for (int r = 0; r < 4; ++r)
      op[r * HW_] = fmaxf(acc[r] * s3[r] + sh3[r], 0.f);
  }
}

extern "C" void kernel_launch(void* const* d_in, const int* in_sizes, int n_in,
                              void* d_out, int out_size, void* d_ws, size_t ws_size,
                              hipStream_t stream) {
  const float* guide    = (const float*)d_in[0];
  const float* target   = (const float*)d_in[1];
  const float* w_reduce = (const float*)d_in[2];
  const float* bn1g     = (const float*)d_in[3];
  const float* bn1b     = (const float*)d_in[4];
  const float* bn1m     = (const float*)d_in[5];
  const float* bn1v     = (const float*)d_in[6];
  const float* w_span   = (const float*)d_in[7];
  const float* b_span   = (const float*)d_in[8];
  const float* w_bconv  = (const float*)d_in[9];
  const float* bn3g     = (const float*)d_in[10];
  const float* bn3b     = (const float*)d_in[11];
  const float* bn3m     = (const float*)d_in[12];
  const float* bn3v     = (const float*)d_in[13];
  float* out = (float*)d_out;

  unsigned short* afrag = (unsigned short*)d_ws;                       // 73728 B
  unsigned short* inv   = (unsigned short*)((char*)d_ws + (1 << 17));  // 16 MiB NHWC bf16

  hipLaunchKernelGGL(k0_prep, dim3(144), dim3(256), 0, stream, w_bconv, afrag);
  hipLaunchKernelGGL(k1_fused, dim3(W_ / 16, H_ / 16, B_), dim3(256), 0, stream,
                     guide, target, w_reduce, bn1g, bn1b, bn1m, bn1v,
                     w_span, b_span, inv);
  hipLaunchKernelGGL(k2_conv, dim3(W_ / 32, H_ / 8, B_), dim3(256), 0, stream,
                     inv, afrag, bn3g, bn3b, bn3m, bn3v, out);
}

// Round 5
// 166.177 us; speedup vs baseline: 1.2581x; 1.2581x over previous
//
#include <hip/hip_runtime.h>

#define B_  8
#define C_  64
#define H_  128
#define W_  128
#define HW_ (H_*W_)
#define NP_ ((size_t)B_*HW_)   // total pixels = 131072

typedef __attribute__((ext_vector_type(4)))  float f32x4;
typedef __attribute__((ext_vector_type(16))) float f32x16;
typedef __attribute__((ext_vector_type(8)))  short short8;

static __device__ __forceinline__ unsigned short f2bf(float f) {
  unsigned int u = __float_as_uint(f);
  u += 0x7fff + ((u >> 16) & 1);   // round-to-nearest-even
  return (unsigned short)(u >> 16);
}
static __device__ __forceinline__ float bf2f(unsigned short u) {
  return __uint_as_float((unsigned int)u << 16);
}

// ---------------- kernel 0: weight prep ----------------
// afrag for mfma_f32_32x32x16_bf16, A = weights (m=oc, k=ic):
//   m = lane&31, k = (lane>>5)*8 + j   (self-consistent with B-side mapping)
// layout: frag fs = ((mh*9 + kk)*4 + ks16), elem = (fs*64 + lane)*8 + j
// also precompute bn3 scale/shift.
__global__ void k0_prep(const float* __restrict__ w,
                        const float* __restrict__ g3, const float* __restrict__ b3,
                        const float* __restrict__ m3, const float* __restrict__ v3,
                        unsigned short* __restrict__ afrag,
                        float* __restrict__ s3, float* __restrict__ sh3) {
  int idx = blockIdx.x * 256 + threadIdx.x;
  if (idx < 36864) {
    int j    = idx & 7;
    int lane = (idx >> 3) & 63;
    int fs   = idx >> 9;          // 0..71
    int ks16 = fs & 3;
    int kk   = (fs >> 2) % 9;
    int mh   = fs / 36;
    int oc = mh * 32 + (lane & 31);
    int ic = ks16 * 16 + (lane >> 5) * 8 + j;
    afrag[idx] = f2bf(w[(oc * 64 + ic) * 9 + kk]);
  } else if (idx < 36864 + 64) {
    int c = idx - 36864;
    float s = g3[c] * rsqrtf(v3[c] + 1e-5f);
    s3[c]  = s;
    sh3[c] = b3[c] - m3[c] * s;
  }
}

// ---------------- kernel 1: fused kernel-gen + involution ----------------
// block 256 = 16x16 pixel tile. Target tile (18x18 halo x 64ch) staged to LDS
// bf16 as [cell][chunk-of-8-ch], chunk slot XOR-swizzled by (cell&7) so the
// per-pixel b128 reads (128B pixel stride) spread across banks.
// inv written chunk-major: inv[(c8*NP + pixel)*8 shorts].
__global__ __launch_bounds__(256) void k1_fused(
    const float* __restrict__ guide, const float* __restrict__ target,
    const float* __restrict__ w_reduce, const float* __restrict__ bn1g,
    const float* __restrict__ bn1b, const float* __restrict__ bn1m,
    const float* __restrict__ bn1v, const float* __restrict__ w_span,
    const float* __restrict__ b_span, unsigned short* __restrict__ inv) {
  __shared__ __align__(16) unsigned short t16[324 * 64];   // 41472 B
  __shared__ f32x4 s_wred[64][4];
  __shared__ f32x4 s_wspan[18][4];
  __shared__ float s_s1[16], s_sh1[16], s_bsp[18];
  int t = threadIdx.x;
  for (int i = t; i < 1024; i += 256) {
    int c = i >> 4, r = i & 15;
    ((float*)&s_wred[c][0])[r] = w_reduce[r * 64 + c];
  }
  for (int i = t; i < 288; i += 256) {
    int j = i / 16, r = i % 16;
    ((float*)&s_wspan[j][0])[r] = w_span[j * 16 + r];
  }
  if (t < 16) {
    float s = bn1g[t] * rsqrtf(bn1v[t] + 1e-5f);
    s_s1[t]  = s;
    s_sh1[t] = bn1b[t] - bn1m[t] * s;
  }
  if (t < 18) s_bsp[t] = b_span[t];

  int b  = blockIdx.z;
  int h0 = blockIdx.y * 16, w0 = blockIdx.x * 16;
  const float* tb = target + (size_t)b * C_ * HW_;

  // stage target tile -> LDS bf16, [cell][swizzled chunk].
  // i = c8*324 + cell: lanes walk cells (coalesced global), one b128 write each.
  for (int i = t; i < 2592; i += 256) {
    int c8 = i / 324, cell = i - c8 * 324;
    int r = cell / 18, col = cell - r * 18;
    int hh = h0 + r - 1, ww = w0 + col - 1;
    short8 val = {0, 0, 0, 0, 0, 0, 0, 0};
    if ((unsigned)hh < (unsigned)H_ && (unsigned)ww < (unsigned)W_) {
      const float* src = tb + (size_t)(c8 * 8) * HW_ + hh * W_ + ww;
      #pragma unroll
      for (int ci = 0; ci < 8; ++ci) val[ci] = (short)f2bf(src[(size_t)ci * HW_]);
    }
    *(short8*)&t16[cell * 64 + ((c8 ^ (cell & 7)) * 8)] = val;
  }
  __syncthreads();

  int ty = t >> 4, tx = t & 15;
  const float* gp = guide + (size_t)b * C_ * HW_ + (h0 + ty) * W_ + (w0 + tx);
  int cell1 = (ty + 1) * 18 + (tx + 1);

  // phase A: reduce conv (guide from global, target from LDS, 8ch per b128)
  f32x4 xr[4];
  xr[0] = 0.f; xr[1] = 0.f; xr[2] = 0.f; xr[3] = 0.f;
  #pragma unroll
  for (int c8 = 0; c8 < 8; ++c8) {
    short8 tv = *(const short8*)&t16[cell1 * 64 + ((c8 ^ (cell1 & 7)) * 8)];
    #pragma unroll
    for (int ci = 0; ci < 8; ++ci) {
      int c = c8 * 8 + ci;
      float v = gp[(size_t)c * HW_] + bf2f((unsigned short)tv[ci]);
      #pragma unroll
      for (int q = 0; q < 4; ++q) xr[q] += s_wred[c][q] * v;
    }
  }
  #pragma unroll
  for (int q = 0; q < 4; ++q) {
    #pragma unroll
    for (int r = 0; r < 4; ++r) {
      float x = xr[q][r] * s_s1[q * 4 + r] + s_sh1[q * 4 + r];
      xr[q][r] = fmaxf(x, 0.f);
    }
  }
  // phase B: span conv -> kern[18]
  float kern[18];
  #pragma unroll
  for (int j = 0; j < 18; ++j) {
    f32x4 a = s_wspan[j][0] * xr[0] + s_wspan[j][1] * xr[1]
            + s_wspan[j][2] * xr[2] + s_wspan[j][3] * xr[3];
    kern[j] = s_bsp[j] + a[0] + a[1] + a[2] + a[3];
  }

  // phase C: involution from LDS (8ch per b128), write chunk-major bf16
  size_t pix = ((size_t)b * H_ + (h0 + ty)) * W_ + (w0 + tx);
  #pragma unroll
  for (int c8 = 0; c8 < 8; ++c8) {
    const float* kb = &kern[(c8 >> 2) * 9];
    float acc[8];
    #pragma unroll
    for (int ci = 0; ci < 8; ++ci) acc[ci] = 0.f;
    #pragma unroll
    for (int di = 0; di < 3; ++di) {
      #pragma unroll
      for (int dj = 0; dj < 3; ++dj) {
        int cell = (ty + di) * 18 + (tx + dj);
        short8 tv = *(const short8*)&t16[cell * 64 + ((c8 ^ (cell & 7)) * 8)];
        float k = kb[di * 3 + dj];
        #pragma unroll
        for (int ci = 0; ci < 8; ++ci) acc[ci] += k * bf2f((unsigned short)tv[ci]);
      }
    }
    short8 pv;
    #pragma unroll
    for (int ci = 0; ci < 8; ++ci) pv[ci] = (short)f2bf(acc[ci]);
    *(short8*)(inv + ((size_t)c8 * NP_ + pix) * 8) = pv;
  }
}

// ---------------- kernel 2: 3x3 conv via mfma_32x32x16 + BN3 + ReLU ----------
// block 256 = 4 waves; tile = 64 oc x 4 rows x 32 w. wave: mh = w&1 (oc half),
// rows rp=(w>>1)*2 .. +1 (two 32-px n-tiles sharing A weights).
// LDS: 6 rows x 34 cols x 128B, chunk XOR-swizzled by (col&7).
__global__ __launch_bounds__(256, 4) void k2_conv(
    const unsigned short* __restrict__ inv, const unsigned short* __restrict__ afrag,
    const float* __restrict__ s3g, const float* __restrict__ sh3g,
    float* __restrict__ out) {
  __shared__ __align__(16) unsigned short tile[204 * 64];   // 26112 B
  int t = threadIdx.x;
  int b  = blockIdx.z;
  int h0 = blockIdx.y * 4;
  int w0 = blockIdx.x * 32;

  // stage inv tile (chunk-major source) with halo
  #pragma unroll
  for (int chunk = 0; chunk < 8; ++chunk) {
    if (t < 204) {
      int r = t / 34, col = t - r * 34;
      int hh = h0 + r - 1, ww = w0 + col - 1;
      short8 val = {0, 0, 0, 0, 0, 0, 0, 0};
      if ((unsigned)hh < (unsigned)H_ && (unsigned)ww < (unsigned)W_)
        val = *(const short8*)(inv + ((size_t)chunk * NP_ + ((size_t)b * H_ + hh) * W_ + ww) * 8);
      *(short8*)&tile[t * 64 + ((chunk ^ (col & 7)) * 8)] = val;
    }
  }

  int wave = t >> 6, lane = t & 63;
  int mh = wave & 1;
  int rp = (wave >> 1) * 2;
  __syncthreads();

  f32x16 acc0, acc1;
  #pragma unroll
  for (int i = 0; i < 16; ++i) { acc0[i] = 0.f; acc1[i] = 0.f; }

  for (int kk = 0; kk < 9; ++kk) {
    int di = kk / 3, dj = kk - di * 3;
    const unsigned short* ap = afrag + (((size_t)(mh * 9 + kk) * 4) * 64 + lane) * 8;
    short8 A0 = *(const short8*)(ap);
    short8 A1 = *(const short8*)(ap + 512);
    short8 A2 = *(const short8*)(ap + 1024);
    short8 A3 = *(const short8*)(ap + 1536);
    int col = (lane & 31) + dj;                 // 0..33
    int swb = (lane >> 5);
    int cb0 = (rp + di) * 34 + col;             // row for nt=0
    #pragma unroll
    for (int ks = 0; ks < 4; ++ks) {
      int sw = ((ks * 2 + swb) ^ (col & 7)) * 8;
      short8 b0 = *(const short8*)&tile[cb0 * 64 + sw];
      short8 b1 = *(const short8*)&tile[(cb0 + 34) * 64 + sw];
      short8 Ak = (ks == 0) ? A0 : (ks == 1) ? A1 : (ks == 2) ? A2 : A3;
      acc0 = __builtin_amdgcn_mfma_f32_32x32x16_bf16(Ak, b0, acc0, 0, 0, 0);
      acc1 = __builtin_amdgcn_mfma_f32_32x32x16_bf16(Ak, b1, acc1, 0, 0, 0);
    }
  }

  // epilogue: BN3 + ReLU, NCHW f32
  int wcol = lane & 31;
  #pragma unroll
  for (int reg = 0; reg < 16; ++reg) {
    int oc = mh * 32 + (reg & 3) + 8 * (reg >> 2) + 4 * (lane >> 5);
    float s  = s3g[oc];
    float sh = sh3g[oc];
    float* op = out + ((size_t)b * C_ + oc) * HW_ + (h0 + rp) * W_ + w0 + wcol;
    op[0]  = fmaxf(acc0[reg] * s + sh, 0.f);
    op[W_] = fmaxf(acc1[reg] * s + sh, 0.f);
  }
}

extern "C" void kernel_launch(void* const* d_in, const int* in_sizes, int n_in,
                              void* d_out, int out_size, void* d_ws, size_t ws_size,
                              hipStream_t stream) {
  const float* guide    = (const float*)d_in[0];
  const float* target   = (const float*)d_in[1];
  const float* w_reduce = (const float*)d_in[2];
  const float* bn1g     = (const float*)d_in[3];
  const float* bn1b     = (const float*)d_in[4];
  const float* bn1m     = (const float*)d_in[5];
  const float* bn1v     = (const float*)d_in[6];
  const float* w_span   = (const float*)d_in[7];
  const float* b_span   = (const float*)d_in[8];
  const float* w_bconv  = (const float*)d_in[9];
  const float* bn3g     = (const float*)d_in[10];
  const float* bn3b     = (const float*)d_in[11];
  const float* bn3m     = (const float*)d_in[12];
  const float* bn3v     = (const float*)d_in[13];
  float* out = (float*)d_out;

  unsigned short* afrag = (unsigned short*)d_ws;                        // 73728 B
  float* s3  = (float*)((char*)d_ws + 73728);                           // 256 B
  float* sh3 = (float*)((char*)d_ws + 73728 + 256);                     // 256 B
  unsigned short* inv   = (unsigned short*)((char*)d_ws + (1 << 17));   // 16.8 MB chunk-major bf16

  hipLaunchKernelGGL(k0_prep, dim3(145), dim3(256), 0, stream,
                     w_bconv, bn3g, bn3b, bn3m, bn3v, afrag, s3, sh3);
  hipLaunchKernelGGL(k1_fused, dim3(W_ / 16, H_ / 16, B_), dim3(256), 0, stream,
                     guide, target, w_reduce, bn1g, bn1b, bn1m, bn1v,
                     w_span, b_span, inv);
  hipLaunchKernelGGL(k2_conv, dim3(W_ / 32, H_ / 4, B_), dim3(256), 0, stream,
                     inv, afrag, s3, sh3, out);
}

// Round 6
// 164.531 us; speedup vs baseline: 1.2707x; 1.0100x over previous
//
#include <hip/hip_runtime.h>

#define B_  8
#define C_  64
#define H_  128
#define W_  128
#define HW_ (H_*W_)
#define NP_ ((size_t)B_*HW_)   // total pixels = 131072

typedef __attribute__((ext_vector_type(4)))  float f32x4;
typedef __attribute__((ext_vector_type(16))) float f32x16;
typedef __attribute__((ext_vector_type(8)))  short short8;

static __device__ __forceinline__ unsigned short f2bf(float f) {
  unsigned int u = __float_as_uint(f);
  u += 0x7fff + ((u >> 16) & 1);   // round-to-nearest-even
  return (unsigned short)(u >> 16);
}
static __device__ __forceinline__ float bf2f(unsigned short u) {
  return __uint_as_float((unsigned int)u << 16);
}

// ---------------- kernel 0: weight prep ----------------
// afrag (k2 conv weights) for mfma_f32_32x32x16_bf16: m=oc=lane&31,
//   k=ic=ks16*16+(lane>>5)*8+j; frag fs=((mh*9+kk)*4+ks16).
// afrag_red (k1 reduce weights): m=red_r (0..15, pad 32), k=ic.
// s3/sh3: folded BN3.
__global__ void k0_prep(const float* __restrict__ w, const float* __restrict__ wred,
                        const float* __restrict__ g3, const float* __restrict__ b3,
                        const float* __restrict__ m3, const float* __restrict__ v3,
                        unsigned short* __restrict__ afrag,
                        unsigned short* __restrict__ afrag_red,
                        float* __restrict__ s3, float* __restrict__ sh3) {
  int idx = blockIdx.x * 256 + threadIdx.x;
  if (idx < 36864) {
    int j    = idx & 7;
    int lane = (idx >> 3) & 63;
    int fs   = idx >> 9;          // 0..71
    int ks16 = fs & 3;
    int kk   = (fs >> 2) % 9;
    int mh   = fs / 36;
    int oc = mh * 32 + (lane & 31);
    int ic = ks16 * 16 + (lane >> 5) * 8 + j;
    afrag[idx] = f2bf(w[(oc * 64 + ic) * 9 + kk]);
  } else if (idx < 38912) {
    int i2 = idx - 36864;         // 0..2047
    int j    = i2 & 7;
    int lane = (i2 >> 3) & 63;
    int ks   = i2 >> 9;           // 0..3
    int m  = lane & 31;
    int ic = ks * 16 + (lane >> 5) * 8 + j;
    afrag_red[i2] = (m < 16) ? f2bf(wred[m * 64 + ic]) : (unsigned short)0;
  } else if (idx < 38976) {
    int c = idx - 38912;
    float s = g3[c] * rsqrtf(v3[c] + 1e-5f);
    s3[c]  = s;
    sh3[c] = b3[c] - m3[c] * s;
  }
}

// ---------------- kernel 1: fused kernel-gen + involution ----------------
// 512 threads = 8 waves; 16x16 pixel tile; 2 lanes per pixel (half h=lane>>5
// owns channels h*32..+31 / chunks 4h..4h+3 / kern group h).
// Wave w owns pixels 32w..32w+31; kernel-gen via mfma_32x32x16 (w_reduce = A).
// Target tile (18x18 halo x 64ch) in LDS bf16 [cell][chunk^swz].
__global__ __launch_bounds__(512, 4) void k1_fused(
    const float* __restrict__ guide, const float* __restrict__ target,
    const unsigned short* __restrict__ afrag_red,
    const float* __restrict__ bn1g, const float* __restrict__ bn1b,
    const float* __restrict__ bn1m, const float* __restrict__ bn1v,
    const float* __restrict__ w_span, const float* __restrict__ b_span,
    unsigned short* __restrict__ inv) {
  __shared__ __align__(16) unsigned short t16[324 * 64];   // 41472 B
  __shared__ f32x4 s_wspan[18][4];                         // [j][quad]
  __shared__ f32x4 s_s1v[4], s_sh1v[4];
  __shared__ float s_bsp[18];
  int t = threadIdx.x;
  if (t < 288) {
    int j = t >> 4, r = t & 15;
    ((float*)&s_wspan[j][0])[r] = w_span[t];     // w_span[j*16+r]
  }
  if (t < 16) {
    float s = bn1g[t] * rsqrtf(bn1v[t] + 1e-5f);
    ((float*)s_s1v)[t]  = s;
    ((float*)s_sh1v)[t] = bn1b[t] - bn1m[t] * s;
  }
  if (t < 18) s_bsp[t] = b_span[t];

  int b  = blockIdx.z;
  int h0 = blockIdx.y * 16, w0 = blockIdx.x * 16;
  const float* tb = target + (size_t)b * C_ * HW_;

  // stage target tile -> LDS bf16 [cell][chunk^ (cell&7)]
  for (int i = t; i < 2592; i += 512) {
    int c8 = i / 324, cell = i - c8 * 324;
    int r = cell / 18, col = cell - r * 18;
    int hh = h0 + r - 1, ww = w0 + col - 1;
    short8 val = {0, 0, 0, 0, 0, 0, 0, 0};
    if ((unsigned)hh < (unsigned)H_ && (unsigned)ww < (unsigned)W_) {
      const float* src = tb + (size_t)(c8 * 8) * HW_ + hh * W_ + ww;
      #pragma unroll
      for (int ci = 0; ci < 8; ++ci) val[ci] = (short)f2bf(src[(size_t)ci * HW_]);
    }
    *(short8*)&t16[cell * 64 + ((c8 ^ (cell & 7)) * 8)] = val;
  }

  int wave = t >> 6, l = t & 63, h = l >> 5;
  // reduce-weight A-fragments (4 K-steps)
  short8 a_red[4];
  #pragma unroll
  for (int ks = 0; ks < 4; ++ks)
    a_red[ks] = *(const short8*)(afrag_red + ((size_t)(ks * 64 + l)) * 8);
  __syncthreads();

  int p   = wave * 32 + (l & 31);          // this lane's pixel (0..255)
  int tyP = p >> 4, txP = p & 15;
  const float* gpx = guide + (size_t)b * C_ * HW_ + (h0 + tyP) * W_ + (w0 + txP);
  int cellC = (tyP + 1) * 18 + (txP + 1);

  // phase A: reduce conv via MFMA. B-frag: lane -> pixel p, channels h*8+ks*16+j
  f32x16 xa;
  #pragma unroll
  for (int i = 0; i < 16; ++i) xa[i] = 0.f;
  #pragma unroll
  for (int ks = 0; ks < 4; ++ks) {
    short8 tvv = *(const short8*)&t16[cellC * 64 + (((2 * ks + h) ^ (cellC & 7)) * 8)];
    int ch0 = ks * 16 + h * 8;
    short8 bf;
    #pragma unroll
    for (int j = 0; j < 8; ++j)
      bf[j] = (short)f2bf(gpx[(size_t)(ch0 + j) * HW_] + bf2f((unsigned short)tvv[j]));
    xa = __builtin_amdgcn_mfma_f32_32x32x16_bf16(a_red[ks], bf, xa, 0, 0, 0);
  }
  // BN1 + ReLU on the 8 valid rows: quads h (rows 4h..) and 2+h (rows 8+4h..)
  f32x4 x0, x1;
  #pragma unroll
  for (int r = 0; r < 4; ++r) { x0[r] = xa[r]; x1[r] = xa[4 + r]; }
  {
    f32x4 sA = s_s1v[h], shA = s_sh1v[h], sB = s_s1v[2 + h], shB = s_sh1v[2 + h];
    #pragma unroll
    for (int r = 0; r < 4; ++r) {
      x0[r] = fmaxf(x0[r] * sA[r] + shA[r], 0.f);
      x1[r] = fmaxf(x1[r] * sB[r] + shB[r], 0.f);
    }
  }

  // phase B: span conv. Each lane computes partials for its group (jA) and
  // partner's group (jB); one shfl_xor(32) completes both dot products.
  float kg[9];
  #pragma unroll
  for (int j9 = 0; j9 < 9; ++j9) {
    int jA = h * 9 + j9;          // own group
    int jB = (9 - 9 * h) + j9;    // partner's group (h=0 -> 9.., h=1 -> 0..)
    f32x4 wA0 = s_wspan[jA][h],     wA1 = s_wspan[jA][2 + h];
    f32x4 wB0 = s_wspan[jB][h],     wB1 = s_wspan[jB][2 + h];
    float pa = 0.f, pb = 0.f;
    #pragma unroll
    for (int r = 0; r < 4; ++r) {
      pa += wA0[r] * x0[r] + wA1[r] * x1[r];
      pb += wB0[r] * x0[r] + wB1[r] * x1[r];
    }
    float recv = __shfl_xor(pb, 32, 64);   // partner's partial for MY group
    kg[j9] = pa + recv + s_bsp[jA];
  }

  // phase C: involution for chunks c8 = 4h..4h+3 of pixel p
  size_t pix = ((size_t)b * H_ + (h0 + tyP)) * W_ + (w0 + txP);
  #pragma unroll
  for (int i = 0; i < 4; ++i) {
    int c8 = h * 4 + i;
    float a8[8];
    #pragma unroll
    for (int ci = 0; ci < 8; ++ci) a8[ci] = 0.f;
    #pragma unroll
    for (int di = 0; di < 3; ++di) {
      #pragma unroll
      for (int dj = 0; dj < 3; ++dj) {
        int cell = (tyP + di) * 18 + (txP + dj);
        short8 tv = *(const short8*)&t16[cell * 64 + ((c8 ^ (cell & 7)) * 8)];
        float k = kg[di * 3 + dj];
        #pragma unroll
        for (int ci = 0; ci < 8; ++ci) a8[ci] += k * bf2f((unsigned short)tv[ci]);
      }
    }
    short8 pv;
    #pragma unroll
    for (int ci = 0; ci < 8; ++ci) pv[ci] = (short)f2bf(a8[ci]);
    *(short8*)(inv + ((size_t)c8 * NP_ + pix) * 8) = pv;
  }
}

// ---------------- kernel 2: 3x3 conv via mfma_32x32x16 + BN3 + ReLU ----------
// block 256 = 4 waves; tile = 64 oc x 4 rows x 32 w. wave: mh = w&1 (oc half),
// rows rp=(w>>1)*2 .. +1 (two 32-px n-tiles sharing A weights).
// LDS: 6 rows x 34 cols x 128B, chunk XOR-swizzled by (col&7).
__global__ __launch_bounds__(256, 4) void k2_conv(
    const unsigned short* __restrict__ inv, const unsigned short* __restrict__ afrag,
    const float* __restrict__ s3g, const float* __restrict__ sh3g,
    float* __restrict__ out) {
  __shared__ __align__(16) unsigned short tile[204 * 64];   // 26112 B
  int t = threadIdx.x;
  int b  = blockIdx.z;
  int h0 = blockIdx.y * 4;
  int w0 = blockIdx.x * 32;

  // stage inv tile (chunk-major source) with halo
  #pragma unroll
  for (int chunk = 0; chunk < 8; ++chunk) {
    if (t < 204) {
      int r = t / 34, col = t - r * 34;
      int hh = h0 + r - 1, ww = w0 + col - 1;
      short8 val = {0, 0, 0, 0, 0, 0, 0, 0};
      if ((unsigned)hh < (unsigned)H_ && (unsigned)ww < (unsigned)W_)
        val = *(const short8*)(inv + ((size_t)chunk * NP_ + ((size_t)b * H_ + hh) * W_ + ww) * 8);
      *(short8*)&tile[t * 64 + ((chunk ^ (col & 7)) * 8)] = val;
    }
  }

  int wave = t >> 6, lane = t & 63;
  int mh = wave & 1;
  int rp = (wave >> 1) * 2;
  __syncthreads();

  f32x16 acc0, acc1;
  #pragma unroll
  for (int i = 0; i < 16; ++i) { acc0[i] = 0.f; acc1[i] = 0.f; }

  for (int kk = 0; kk < 9; ++kk) {
    int di = kk / 3, dj = kk - di * 3;
    const unsigned short* ap = afrag + (((size_t)(mh * 9 + kk) * 4) * 64 + lane) * 8;
    short8 A0 = *(const short8*)(ap);
    short8 A1 = *(const short8*)(ap + 512);
    short8 A2 = *(const short8*)(ap + 1024);
    short8 A3 = *(const short8*)(ap + 1536);
    int col = (lane & 31) + dj;                 // 0..33
    int swb = (lane >> 5);
    int cb0 = (rp + di) * 34 + col;             // row for nt=0
    #pragma unroll
    for (int ks = 0; ks < 4; ++ks) {
      int sw = ((ks * 2 + swb) ^ (col & 7)) * 8;
      short8 b0 = *(const short8*)&tile[cb0 * 64 + sw];
      short8 b1 = *(const short8*)&tile[(cb0 + 34) * 64 + sw];
      short8 Ak = (ks == 0) ? A0 : (ks == 1) ? A1 : (ks == 2) ? A2 : A3;
      acc0 = __builtin_amdgcn_mfma_f32_32x32x16_bf16(Ak, b0, acc0, 0, 0, 0);
      acc1 = __builtin_amdgcn_mfma_f32_32x32x16_bf16(Ak, b1, acc1, 0, 0, 0);
    }
  }

  // epilogue: BN3 + ReLU, NCHW f32
  int wcol = lane & 31;
  #pragma unroll
  for (int reg = 0; reg < 16; ++reg) {
    int oc = mh * 32 + (reg & 3) + 8 * (reg >> 2) + 4 * (lane >> 5);
    float s  = s3g[oc];
    float sh = sh3g[oc];
    float* op = out + ((size_t)b * C_ + oc) * HW_ + (h0 + rp) * W_ + w0 + wcol;
    op[0]  = fmaxf(acc0[reg] * s + sh, 0.f);
    op[W_] = fmaxf(acc1[reg] * s + sh, 0.f);
  }
}

extern "C" void kernel_launch(void* const* d_in, const int* in_sizes, int n_in,
                              void* d_out, int out_size, void* d_ws, size_t ws_size,
                              hipStream_t stream) {
  const float* guide    = (const float*)d_in[0];
  const float* target   = (const float*)d_in[1];
  const float* w_reduce = (const float*)d_in[2];
  const float* bn1g     = (const float*)d_in[3];
  const float* bn1b     = (const float*)d_in[4];
  const float* bn1m     = (const float*)d_in[5];
  const float* bn1v     = (const float*)d_in[6];
  const float* w_span   = (const float*)d_in[7];
  const float* b_span   = (const float*)d_in[8];
  const float* w_bconv  = (const float*)d_in[9];
  const float* bn3g     = (const float*)d_in[10];
  const float* bn3b     = (const float*)d_in[11];
  const float* bn3m     = (const float*)d_in[12];
  const float* bn3v     = (const float*)d_in[13];
  float* out = (float*)d_out;

  unsigned short* afrag     = (unsigned short*)d_ws;                      // 73728 B
  unsigned short* afrag_red = (unsigned short*)((char*)d_ws + 81920);     // 4096 B
  float* s3  = (float*)((char*)d_ws + 90112);                             // 256 B
  float* sh3 = (float*)((char*)d_ws + 90368);                             // 256 B
  unsigned short* inv = (unsigned short*)((char*)d_ws + (1 << 17));       // 16.8 MB

  hipLaunchKernelGGL(k0_prep, dim3(153), dim3(256), 0, stream,
                     w_bconv, w_reduce, bn3g, bn3b, bn3m, bn3v,
                     afrag, afrag_red, s3, sh3);
  hipLaunchKernelGGL(k1_fused, dim3(W_ / 16, H_ / 16, B_), dim3(512), 0, stream,
                     guide, target, afrag_red, bn1g, bn1b, bn1m, bn1v,
                     w_span, b_span, inv);
  hipLaunchKernelGGL(k2_conv, dim3(W_ / 32, H_ / 4, B_), dim3(256), 0, stream,
                     inv, afrag, s3, sh3, out);
}